// Round 6
// baseline (104.951 us; speedup 1.0000x reference)
//
#include <hip/hip_runtime.h>
#include <stdint.h>

// Bahdanau attention: B=64, T=2048, D=256, U=256, all fp32 in/out.
// out = [context (B*D) | attn (B*T)] flat fp32.
#define Bq 64
#define Tq 2048
#define Dq 256
#define Uq 256

typedef __bf16 bf16x8 __attribute__((ext_vector_type(8)));
typedef float f32x4 __attribute__((ext_vector_type(4)));

// A LDS geometry (per wave): [pl 0..1][oct 0..3][row 0..31][16B], oct stride 528B (pad)
#define AOCT 528
#define APL  (4 * AOCT)     // 2112
#define AWV  (2 * APL)      // 4224 per wave

// split fp32 into truncated-bf16 hi + bf16(lo) residual. a = hi + lo + O(2^-16 |a|)
__device__ inline void split2(float a, unsigned short& h, unsigned short& l) {
  unsigned bits = __float_as_uint(a);
  h = (unsigned short)(bits >> 16);
  float hf = __uint_as_float(bits & 0xffff0000u);
  l = (unsigned short)(__float_as_uint(a - hf) >> 16);
}

// tanh(x) = 1 - 2/(exp(2x)+1). ~6 VALU ops, saturates correctly.
__device__ inline float fast_tanh(float x) {
  float e = __expf(2.0f * x);
  return 1.0f - 2.0f * __builtin_amdgcn_rcpf(e + 1.0f);
}

// K0: split w1 [U][D] fp32 -> bf16 hi/lo planes, stored OCTET-MAJOR:
// plane[(k>>3)*U*8 + u*8 + (k&7)]
__global__ void k0_split(const float* __restrict__ w1,
                         unsigned short* __restrict__ hi,
                         unsigned short* __restrict__ lo) {
  int idx = blockIdx.x * 256 + threadIdx.x;
  int i = idx * 4;
  int u = i >> 8;
  int k = i & 255;
  float4 v = *reinterpret_cast<const float4*>(&w1[i]);
  ushort4 h, l;
  split2(v.x, h.x, l.x);
  split2(v.y, h.y, l.y);
  split2(v.z, h.z, l.z);
  split2(v.w, h.w, l.w);
  int dst = (k >> 3) * (Uq * 8) + u * 8 + (k & 7);
  *reinterpret_cast<ushort4*>(&hi[dst]) = h;
  *reinterpret_cast<ushort4*>(&lo[dst]) = l;
}

// K1: comb[b][u] = dot(hidden[b], w2_w[u]) + w2_b[u] + w1_b[u]
__global__ void k1_comb(const float* __restrict__ hidden,
                        const float* __restrict__ w2_w,
                        const float* __restrict__ w2_b,
                        const float* __restrict__ w1_b,
                        float* __restrict__ comb) {
  int b = blockIdx.x;
  int wave = threadIdx.x >> 6;
  int lane = threadIdx.x & 63;
  int u = blockIdx.y * 4 + wave;
  const float* h = hidden + b * Dq;
  const float* w = w2_w + u * Dq;
  float sum = 0.f;
#pragma unroll
  for (int i = 0; i < Dq; i += 64) sum += h[lane + i] * w[lane + i];
#pragma unroll
  for (int m = 32; m >= 1; m >>= 1) sum += __shfl_xor(sum, m, 64);
  if (lane == 0) comb[b * Uq + u] = sum + w2_b[u] + w1_b[u];
}

// K2: partial score over a 64-u slice. Barrier-free main loop:
// - w1-hi slice (64u x 256k) DMA'd to LDS once (one barrier), read-only after.
// - w1-lo read per chunk from L1/L2-resident global.
// - features staged wave-privately (32 t-rows/wave) -> no inter-wave coupling.
// Block 256 thr = 4 waves; tile 128t x 64u; wave tile 32t x 64u.
// spart[uq][b][t] = sum_{u in slice} v_w[u] * tanh(feat.w1[u] + comb[u])
__global__ __launch_bounds__(256, 3) void k2_score(
    const float* __restrict__ feat, const unsigned short* __restrict__ w1hi,
    const unsigned short* __restrict__ w1lo, const float* __restrict__ comb,
    const float* __restrict__ v_w, float* __restrict__ spart) {
  __shared__ char lB[32 * 1024];   // [ko 0..31][64 u][16B]
  __shared__ char lA[4 * AWV];     // wave-private A regions
  const int b  = blockIdx.z;
  const int uq = blockIdx.y;
  const int u0 = uq * 64;
  const int t0 = blockIdx.x * 128;
  const int tid = threadIdx.x;
  const int w = tid >> 6;
  const int l = tid & 63;
  const int fr = l & 15;
  const int g  = l >> 4;

  // ---- stage B-hi slice into LDS once: 8 x 1KB DMA per wave ----
#pragma unroll
  for (int j = 0; j < 8; ++j) {
    int ko = w * 8 + j;
    const unsigned short* src = w1hi + ko * 2048 + u0 * 8 + l * 8;
    char* dst = lB + ko * 1024;
    __builtin_amdgcn_global_load_lds(
        (const __attribute__((address_space(1))) unsigned int*)src,
        (__attribute__((address_space(3))) unsigned int*)dst, 16, 0, 0);
  }

  // A staging roles: task p in {0,1}: row = (l>>2)+16p, oct = l&3
  const int aoct = l & 3;
  const float* arp0 =
      feat + ((size_t)(b * Tq + t0 + w * 32 + (l >> 2))) * Dq + aoct * 8;
  const float* arp1 = arp0 + 16 * Dq;
  char* aw0 = lA + w * AWV + aoct * AOCT + (l >> 2) * 16;
  char* aw1 = aw0 + 16 * 16;
  const char* arb = lA + w * AWV + g * AOCT;  // frag read base (hi plane)

  // prologue: prefetch chunk-0 features
  float4 pa00 = *reinterpret_cast<const float4*>(arp0);
  float4 pa01 = *reinterpret_cast<const float4*>(arp0 + 4);
  float4 pa10 = *reinterpret_cast<const float4*>(arp1);
  float4 pa11 = *reinterpret_cast<const float4*>(arp1 + 4);

  __syncthreads();  // B-hi DMA + everyone ready (only barrier)

  f32x4 acc[2][4] = {};

  for (int c = 0; c < 8; ++c) {
    const int kc = c * 32;
    // ---- write A(c) hi/lo to this wave's LDS region ----
    {
      float f0[8] = {pa00.x, pa00.y, pa00.z, pa00.w, pa01.x, pa01.y, pa01.z, pa01.w};
      float f1[8] = {pa10.x, pa10.y, pa10.z, pa10.w, pa11.x, pa11.y, pa11.z, pa11.w};
      unsigned short h[8], lo8[8];
      uint4 H, L;
#pragma unroll
      for (int j = 0; j < 8; ++j) split2(f0[j], h[j], lo8[j]);
      H.x = h[0] | (h[1] << 16);   H.y = h[2] | (h[3] << 16);
      H.z = h[4] | (h[5] << 16);   H.w = h[6] | (h[7] << 16);
      L.x = lo8[0] | (lo8[1] << 16); L.y = lo8[2] | (lo8[3] << 16);
      L.z = lo8[4] | (lo8[5] << 16); L.w = lo8[6] | (lo8[7] << 16);
      *reinterpret_cast<uint4*>(aw0) = H;
      *reinterpret_cast<uint4*>(aw0 + APL) = L;
#pragma unroll
      for (int j = 0; j < 8; ++j) split2(f1[j], h[j], lo8[j]);
      H.x = h[0] | (h[1] << 16);   H.y = h[2] | (h[3] << 16);
      H.z = h[4] | (h[5] << 16);   H.w = h[6] | (h[7] << 16);
      L.x = lo8[0] | (lo8[1] << 16); L.y = lo8[2] | (lo8[3] << 16);
      L.z = lo8[4] | (lo8[5] << 16); L.w = lo8[6] | (lo8[7] << 16);
      *reinterpret_cast<uint4*>(aw1) = H;
      *reinterpret_cast<uint4*>(aw1 + APL) = L;
    }
    // ---- B-lo fragments from global (L1/L2-resident slice) ----
    bf16x8 blv[4];
#pragma unroll
    for (int nf = 0; nf < 4; ++nf) {
      size_t off = (size_t)(kc / 8 + g) * 2048 + (u0 + nf * 16 + fr) * 8;
      blv[nf] = *reinterpret_cast<const bf16x8*>(&w1lo[off]);
    }
    // ---- prefetch next chunk's features ----
    if (c < 7) {
      pa00 = *reinterpret_cast<const float4*>(arp0 + kc + 32);
      pa01 = *reinterpret_cast<const float4*>(arp0 + kc + 36);
      pa10 = *reinterpret_cast<const float4*>(arp1 + kc + 32);
      pa11 = *reinterpret_cast<const float4*>(arp1 + kc + 36);
    }
    // ---- A fragments (own region; same-wave lgkm ordering) + B-hi frags ----
    bf16x8 ah[2], al[2], bhv[4];
#pragma unroll
    for (int mf = 0; mf < 2; ++mf) {
      const char* r = arb + (mf * 16 + fr) * 16;
      ah[mf] = *reinterpret_cast<const bf16x8*>(r);
      al[mf] = *reinterpret_cast<const bf16x8*>(r + APL);
    }
#pragma unroll
    for (int nf = 0; nf < 4; ++nf)
      bhv[nf] = *reinterpret_cast<const bf16x8*>(
          lB + (kc / 8 + g) * 1024 + (nf * 16 + fr) * 16);
    // ---- 3-plane MFMA ----
#pragma unroll
    for (int mf = 0; mf < 2; ++mf) {
#pragma unroll
      for (int nf = 0; nf < 4; ++nf) {
        acc[mf][nf] = __builtin_amdgcn_mfma_f32_16x16x32_bf16(
            ah[mf], bhv[nf], acc[mf][nf], 0, 0, 0);
        acc[mf][nf] = __builtin_amdgcn_mfma_f32_16x16x32_bf16(
            ah[mf], blv[nf], acc[mf][nf], 0, 0, 0);
        acc[mf][nf] = __builtin_amdgcn_mfma_f32_16x16x32_bf16(
            al[mf], bhv[nf], acc[mf][nf], 0, 0, 0);
      }
    }
  }

  // epilogue: tanh + v-dot over this block's 64 u; in-wave reduce only.
  // acc[mf][nf][r] is (t_local = w*32 + mf*16 + g*4 + r, u = u0 + nf*16 + fr)
  float cb[4], vw4[4];
#pragma unroll
  for (int nf = 0; nf < 4; ++nf) {
    int u = u0 + nf * 16 + fr;
    cb[nf] = comb[b * Uq + u];
    vw4[nf] = v_w[u];
  }
  float sc[2][4];
#pragma unroll
  for (int mf = 0; mf < 2; ++mf)
#pragma unroll
    for (int r = 0; r < 4; ++r) sc[mf][r] = 0.f;
#pragma unroll
  for (int mf = 0; mf < 2; ++mf)
#pragma unroll
    for (int nf = 0; nf < 4; ++nf)
#pragma unroll
      for (int r = 0; r < 4; ++r)
        sc[mf][r] += vw4[nf] * fast_tanh(acc[mf][nf][r] + cb[nf]);
#pragma unroll
  for (int m = 1; m < 16; m <<= 1)
#pragma unroll
    for (int mf = 0; mf < 2; ++mf)
#pragma unroll
      for (int r = 0; r < 4; ++r) sc[mf][r] += __shfl_xor(sc[mf][r], m, 16);
  if (fr == 0) {
#pragma unroll
    for (int mf = 0; mf < 2; ++mf)
#pragma unroll
      for (int r = 0; r < 4; ++r)
        spart[((size_t)uq * Bq + b) * Tq + t0 + w * 32 + mf * 16 + g * 4 + r] =
            sc[mf][r];
  }
}

// K3: softmax over T per batch; reduces the 4 u-slice partials + v_b first.
__global__ void k3_softmax(const float* __restrict__ spart,
                           const float* __restrict__ v_b,
                           float* __restrict__ s) {
  int b = blockIdx.x;
  int tid = threadIdx.x;
  const int base = b * Tq;
  const int P = Bq * Tq;
  float vb = v_b[0];
  float v[8];
  float m = -1e30f;
#pragma unroll
  for (int i = 0; i < 8; ++i) {
    int idx = base + tid + 256 * i;
    v[i] = spart[idx] + spart[P + idx] + spart[2 * P + idx] + spart[3 * P + idx] + vb;
    m = fmaxf(m, v[i]);
  }
#pragma unroll
  for (int mk = 32; mk >= 1; mk >>= 1) m = fmaxf(m, __shfl_xor(m, mk, 64));
  __shared__ float red[4];
  int wv = tid >> 6, ln = tid & 63;
  if (ln == 0) red[wv] = m;
  __syncthreads();
  m = fmaxf(fmaxf(red[0], red[1]), fmaxf(red[2], red[3]));
  __syncthreads();
  float sum = 0.f;
#pragma unroll
  for (int i = 0; i < 8; ++i) {
    v[i] = __expf(v[i] - m);
    sum += v[i];
  }
#pragma unroll
  for (int mk = 32; mk >= 1; mk >>= 1) sum += __shfl_xor(sum, mk, 64);
  if (ln == 0) red[wv] = sum;
  __syncthreads();
  sum = red[0] + red[1] + red[2] + red[3];
  float inv = 1.f / sum;
#pragma unroll
  for (int i = 0; i < 8; ++i) s[base + tid + 256 * i] = v[i] * inv;
}

// K4a: partial context over a 256-t slice
__global__ void k4_partial(const float* __restrict__ feat,
                           const float* __restrict__ attn,
                           float* __restrict__ part) {
  int b = blockIdx.x;
  int ts = blockIdx.y;
  int d = threadIdx.x;
  const int t0 = ts * 256;
  const float* f = feat + ((size_t)(b * Tq + t0)) * Dq + d;
  const float* a = attn + b * Tq + t0;
  float acc = 0.f;
#pragma unroll 8
  for (int t = 0; t < 256; ++t) acc += a[t] * f[(size_t)t * Dq];
  part[(b * 8 + ts) * Dq + d] = acc;
}

// K4b: reduce the 8 partials
__global__ void k4_reduce(const float* __restrict__ part,
                          float* __restrict__ ctx) {
  int b = blockIdx.x;
  int d = threadIdx.x;
  float s = 0.f;
#pragma unroll
  for (int ts = 0; ts < 8; ++ts) s += part[(b * 8 + ts) * Dq + d];
  ctx[b * Dq + d] = s;
}

extern "C" void kernel_launch(void* const* d_in, const int* in_sizes, int n_in,
                              void* d_out, int out_size, void* d_ws,
                              size_t ws_size, hipStream_t stream) {
  const float* feat   = (const float*)d_in[0];
  const float* hidden = (const float*)d_in[1];
  const float* w1_w   = (const float*)d_in[2];
  const float* w1_b   = (const float*)d_in[3];
  const float* w2_w   = (const float*)d_in[4];
  const float* w2_b   = (const float*)d_in[5];
  const float* v_w    = (const float*)d_in[6];
  const float* v_b    = (const float*)d_in[7];

  float* ctx  = (float*)d_out;             // [B][D]
  float* attn = ctx + Bq * Dq;             // [B][T]
  float* comb = (float*)d_ws;              // [B][U]        64 KB
  float* part = comb + Bq * Uq;            // [B][8][D]     512 KB
  float* spart = part + Bq * 8 * Dq;       // [4][B][T]     2 MB
  unsigned short* w1hi = (unsigned short*)(spart + 4 * Bq * Tq);  // 128 KB
  unsigned short* w1lo = w1hi + Uq * Dq;                          // 128 KB

  k0_split<<<Uq * Dq / 1024, 256, 0, stream>>>(w1_w, w1hi, w1lo);
  k1_comb<<<dim3(Bq, Uq / 4), 256, 0, stream>>>(hidden, w2_w, w2_b, w1_b, comb);
  k2_score<<<dim3(Tq / 128, 4, Bq), 256, 0, stream>>>(feat, w1hi, w1lo, comb,
                                                      v_w, spart);
  k3_softmax<<<Bq, 256, 0, stream>>>(spart, v_b, attn);
  k4_partial<<<dim3(Bq, 8), 256, 0, stream>>>(feat, attn, part);
  k4_reduce<<<Bq, 256, 0, stream>>>(part, ctx);
}